// Round 10
// baseline (273.045 us; speedup 1.0000x reference)
//
#include <hip/hip_runtime.h>
#include <hip/hip_bf16.h>
#include <stdint.h>

#define BATCH 4
#define NPTS  1024
#define CIN   512
#define NS    32
#define P_TOT (BATCH*NPTS*NS)      /* 131072 */
#define CO    512
#define RADIUS_F 0.05f
#define HMIN_F  (-0.02f)
#define HMAX_F  (0.04f)

typedef __attribute__((ext_vector_type(8))) short short8;
typedef __attribute__((ext_vector_type(4))) float f32x4;

__device__ __forceinline__ unsigned short f2bf(float f) {
  unsigned int x = __float_as_uint(f);
  x = x + 0x7fffu + ((x >> 16) & 1u);   // RNE
  return (unsigned short)(x >> 16);
}
__device__ __forceinline__ float bf2f(unsigned short u) {
  return __uint_as_float(((unsigned int)u) << 16);
}
__device__ __forceinline__ unsigned int cvtpk(float lo, float hi) {
  unsigned int r;
  asm("v_cvt_pk_bf16_f32 %0, %1, %2" : "=v"(r) : "v"(lo), "v"(hi));
  return r;   // D[15:0]=bf16(lo), D[31:16]=bf16(hi), RNE
}
__device__ __forceinline__ void load_lds16(const void* g, void* l) {
  __builtin_amdgcn_global_load_lds((const __attribute__((address_space(1))) void*)g,
                                   (__attribute__((address_space(3))) void*)l, 16, 0, 0);
}

// ---------------- cylinder query: idx + local coords (f32) ------------------
__global__ void cyl_query_kernel(const float* __restrict__ xyz,
                                 const float* __restrict__ rot,
                                 int* __restrict__ idxout,
                                 float* __restrict__ lxyz) {
  int bm = blockIdx.x;             // b*1024 + m
  int b = bm >> 10;
  int lane = threadIdx.x;          // 64 threads = 1 wave
  const float* ctr = xyz + (size_t)bm * 3;
  float cx = ctr[0], cy = ctr[1], cz = ctr[2];
  const float* R = rot + (size_t)bm * 9;
  float r00=R[0],r01=R[1],r02=R[2],r10=R[3],r11=R[4],r12=R[5],r20=R[6],r21=R[7],r22=R[8];
  __shared__ int sidx[32];
  int taken = 0;
  for (int base = 0; base < NPTS && taken < NS; base += 64) {
    int n = base + lane;
    const float* p = xyz + ((size_t)b * NPTS + n) * 3;
    float dx = p[0]-cx, dy = p[1]-cy, dz = p[2]-cz;
    float rx = dx*r00 + dy*r10 + dz*r20;
    float ry = dx*r01 + dy*r11 + dz*r21;
    float rz = dx*r02 + dy*r12 + dz*r22;
    bool ok = (ry*ry + rz*rz < RADIUS_F*RADIUS_F) && (rx > HMIN_F) && (rx < HMAX_F);
    unsigned long long bal = __ballot(ok);
    if (ok) {
      int slot = taken + __popcll(bal & ((1ull << lane) - 1ull));
      if (slot < NS) sidx[slot] = n;
    }
    taken += __popcll(bal);
  }
  __syncthreads();
  int filled = taken < NS ? taken : NS;
  if (lane < NS) {
    int nsel = (lane < filled) ? sidx[lane] : sidx[0];
    size_t pp = (size_t)bm * NS + lane;
    idxout[pp] = nsel;
    const float* pn = xyz + ((size_t)b * NPTS + nsel) * 3;
    float dx = pn[0]-cx, dy = pn[1]-cy, dz = pn[2]-cz;
    const float inv = 1.0f / RADIUS_F;
    float rx = (dx*r00 + dy*r10 + dz*r20) * inv;
    float ry = (dx*r01 + dy*r11 + dz*r21) * inv;
    float rz = (dx*r02 + dy*r12 + dz*r22) * inv;
    float* lw = lxyz + pp * 3;
    lw[0] = rx; lw[1] = ry; lw[2] = rz;
  }
}

// ---------------- transpose feats (B,C,N) fp32 -> (B,N,C) bf16 --------------
__global__ void transpose_feats(const float* __restrict__ feats,
                                unsigned short* __restrict__ featsT) {
  __shared__ float tile[64][65];
  int b = blockIdx.z, cb = blockIdx.y, nb = blockIdx.x;
  int t = threadIdx.x, tr = t >> 6, tc = t & 63;
  #pragma unroll
  for (int j = 0; j < 16; ++j) {
    int c = cb*64 + j*4 + tr;
    tile[j*4+tr][tc] = feats[((size_t)b*CIN + c)*NPTS + nb*64 + tc];
  }
  __syncthreads();
  #pragma unroll
  for (int j = 0; j < 16; ++j) {
    int n = nb*64 + j*4 + tr;
    featsT[((size_t)b*NPTS + n)*CIN + cb*64 + tc] = f2bf(tile[tc][j*4+tr]);
  }
}

// ---------------- weight conversion -----------------------------------------
__global__ void build_w1(const float* __restrict__ W1,
                         unsigned short* __restrict__ w1f,
                         float* __restrict__ w1l) {
  int i = blockIdx.x*256 + threadIdx.x;
  if (i < 512*512) {
    int o = i >> 9, k = i & 511;
    w1f[i] = f2bf(W1[o*515 + 3 + k]);
  }
  if (i < 512*3) {
    w1l[i] = W1[(i/3)*515 + (i%3)];
  }
}
__global__ void build_w2(const float* __restrict__ W2, unsigned short* __restrict__ w2b) {
  int i = blockIdx.x*256 + threadIdx.x;
  if (i < CO*CIN) w2b[i] = f2bf(W2[i]);
}

// ============ scatter: per-unique-row local sums + counts + global moments ===
__global__ __launch_bounds__(256) void scatter_kernel(
    const int* __restrict__ idx, const float* __restrict__ lxyz,
    float* __restrict__ L4, float* __restrict__ GM) {
  int i = blockIdx.x*256 + threadIdx.x;   // 512 blocks x 256 = P_TOT
  int b = i >> 15;
  int n = idx[i];
  const float* lw = lxyz + (size_t)i*3;
  float lx = lw[0], ly = lw[1], lz = lw[2];
  float* dst = L4 + (((size_t)b << 10) + n)*4;
  atomicAdd(dst+0, lx); atomicAdd(dst+1, ly);
  atomicAdd(dst+2, lz); atomicAdd(dst+3, 1.0f);
  float m[9] = {lx, ly, lz, lx*lx, lx*ly, lx*lz, ly*ly, ly*lz, lz*lz};
  #pragma unroll
  for (int d = 1; d < 64; d <<= 1)
    #pragma unroll
    for (int e = 0; e < 9; ++e) m[e] += __shfl_xor(m[e], d);
  __shared__ float mred[9];
  if (threadIdx.x < 9) mred[threadIdx.x] = 0.f;
  __syncthreads();
  if ((threadIdx.x & 63) == 0)
    #pragma unroll
    for (int e = 0; e < 9; ++e) atomicAdd(&mred[e], m[e]);
  __syncthreads();
  if (threadIdx.x < 9) atomicAdd(&GM[threadIdx.x], mred[threadIdx.x]);
}

// ============ GEMM1u: unique-point features x W1f^T (fp32 out) ==============
__global__ __launch_bounds__(256) void gemm1u_kernel(
    const unsigned short* __restrict__ A,
    const unsigned short* __restrict__ Bw,
    float* __restrict__ C)
{
  __shared__ unsigned short As[128*32];
  __shared__ unsigned short Bs[128*32];
  int bx = blockIdx.x;
  int ob = bx & 3;
  size_t p0 = (size_t)(bx >> 2) * 128;
  int o0 = ob * 128;
  int t = threadIdx.x;
  int w = t >> 6, lane = t & 63;
  int wr = w >> 1, wc = w & 1;
  int l15 = lane & 15, l4 = lane >> 4;
  f32x4 acc[4][4];
  f32x4 zf = {0.f, 0.f, 0.f, 0.f};
  #pragma unroll
  for (int mi = 0; mi < 4; ++mi)
    #pragma unroll
    for (int ni = 0; ni < 4; ++ni) acc[mi][ni] = zf;

  int c0 = 2*w;
  int srow = lane >> 2;
  int scole = (lane & 3) * 8;

  const unsigned short* abase[2];
  const unsigned short* bbase[2];
  #pragma unroll
  for (int cc = 0; cc < 2; ++cc) {
    int row = 16*(c0+cc) + srow;
    abase[cc] = A + (p0 + row)*(size_t)512 + scole;
    bbase[cc] = Bw + (size_t)(o0 + row)*512 + scole;
  }

  for (int k0 = 0; k0 < 512; k0 += 32) {
    #pragma unroll
    for (int cc = 0; cc < 2; ++cc) {
      int c = c0 + cc;
      load_lds16(abase[cc] + k0, (char*)As + c*1024);
      load_lds16(bbase[cc] + k0, (char*)Bs + c*1024);
    }
    __syncthreads();
    short8 af[4], bfr[4];
    #pragma unroll
    for (int mi = 0; mi < 4; ++mi)
      af[mi] = *(const short8*)(As + (wr*64 + mi*16 + l15)*32 + l4*8);
    #pragma unroll
    for (int ni = 0; ni < 4; ++ni)
      bfr[ni] = *(const short8*)(Bs + (wc*64 + ni*16 + l15)*32 + l4*8);
    #pragma unroll
    for (int mi = 0; mi < 4; ++mi)
      #pragma unroll
      for (int ni = 0; ni < 4; ++ni)
        acc[mi][ni] = __builtin_amdgcn_mfma_f32_16x16x32_bf16(af[mi], bfr[ni], acc[mi][ni], 0, 0, 0);
    __syncthreads();
  }
  #pragma unroll
  for (int mi = 0; mi < 4; ++mi)
    #pragma unroll
    for (int ni = 0; ni < 4; ++ni)
      #pragma unroll
      for (int j = 0; j < 4; ++j) {
        size_t p = p0 + wr*64 + mi*16 + l4*4 + j;
        int o = o0 + wc*64 + ni*16 + l15;
        C[p*512 + o] = acc[mi][ni][j];
      }
}

// ============ stats1: algebraic BN1 sums over u (one h1u read) ==============
__global__ __launch_bounds__(256) void stats1_kernel(
    const float* __restrict__ h1u, const float* __restrict__ L4,
    const float* __restrict__ w1l, float* __restrict__ sums) {
  int t = threadIdx.x;
  int c2 = t*2;
  int u0 = blockIdx.x * 16;
  float w0a = w1l[c2*3],     w1a = w1l[c2*3+1],     w2a = w1l[c2*3+2];
  float w0b = w1l[(c2+1)*3], w1b = w1l[(c2+1)*3+1], w2b = w1l[(c2+1)*3+2];
  float s0=0.f, s1=0.f, q0=0.f, q1=0.f;
  #pragma unroll 4
  for (int j = 0; j < 16; ++j) {
    int u = u0 + j;
    float4 Lc = *(const float4*)(L4 + (size_t)u*4);
    float2 h = *(const float2*)(h1u + (size_t)u*512 + c2);
    float lwa = Lc.x*w0a + Lc.y*w1a + Lc.z*w2a;
    float lwb = Lc.x*w0b + Lc.y*w1b + Lc.z*w2b;
    s0 += Lc.w*h.x;  q0 += Lc.w*h.x*h.x + 2.f*h.x*lwa;
    s1 += Lc.w*h.y;  q1 += Lc.w*h.y*h.y + 2.f*h.y*lwb;
  }
  atomicAdd(&sums[c2],       s0);
  atomicAdd(&sums[c2+1],     s1);
  atomicAdd(&sums[512+c2],   q0);
  atomicAdd(&sums[512+c2+1], q1);
}

// ---- finalize1: BN1 scale/shift + folded local weights w1ls = sc*w1l -------
__global__ void finalize1_kernel(const float* __restrict__ sums,
                                 const float* __restrict__ GM,
                                 const float* __restrict__ w1l,
                                 const float* __restrict__ g,
                                 const float* __restrict__ bia,
                                 float* __restrict__ ss,
                                 float* __restrict__ w1ls) {
  int c = blockIdx.x*256 + threadIdx.x;
  if (c >= 512) return;
  float w0 = w1l[c*3], w1 = w1l[c*3+1], w2 = w1l[c*3+2];
  float S = sums[c] + w0*GM[0] + w1*GM[1] + w2*GM[2];
  float Q = sums[512+c] + w0*w0*GM[3] + 2.f*w0*w1*GM[4] + 2.f*w0*w2*GM[5]
                        + w1*w1*GM[6] + 2.f*w1*w2*GM[7] + w2*w2*GM[8];
  const float invN = 1.f / (float)P_TOT;
  float mean = S * invN;
  float var  = Q * invN - mean*mean;
  float sc = g[c] * rsqrtf(var + 1e-5f);
  ss[c] = sc;
  ss[512+c] = bia[c] - mean*sc;
  w1ls[c]        = sc * w0;   // planar [3][512]
  w1ls[512 + c]  = sc * w1;
  w1ls[1024 + c] = sc * w2;
}

// ---- fold: h1u <- sc*h1u + sh (in place; BN1 affine folded into operand) ---
__global__ __launch_bounds__(256) void fold_kernel(float* __restrict__ h1u,
                                                   const float* __restrict__ ss) {
  size_t i = ((size_t)blockIdx.x*256 + threadIdx.x) * 4;   // 2048 blocks
  int c = (int)(i & 511);
  float4 v = *(float4*)(h1u + i);
  float4 sc = *(const float4*)(ss + c);
  float4 sh = *(const float4*)(ss + 512 + c);
  v.x = fmaf(v.x, sc.x, sh.x);
  v.y = fmaf(v.y, sc.y, sh.y);
  v.z = fmaf(v.z, sc.z, sh.z);
  v.w = fmaf(v.w, sc.w, sh.w);
  *(float4*)(h1u + i) = v;
}

__global__ void finalize_kernel(const float* __restrict__ sums,
                                const float* __restrict__ g,
                                const float* __restrict__ bia,
                                float* __restrict__ ss) {
  int c = blockIdx.x*256 + threadIdx.x;
  if (c >= 512) return;
  const float invN = 1.f / (float)P_TOT;
  float mean = sums[c] * invN;
  float var  = sums[512+c] * invN - mean*mean;
  float sc = g[c] * rsqrtf(var + 1e-5f);
  ss[c] = sc;
  ss[512+c] = bia[c] - mean*sc;
}

// ============ GEMM2 v3: double-buffered one-barrier K-loop ==================
// A = relu(h1u'[u] + l·w1ls) -> bf16, transformed into As[next] while MFMA
// runs on buf[cur]; Bs[next] staged via global_load_lds. ONE barrier/K-step:
// the vmcnt(0) drain at the barrier is covered by transform+MFMA (~300 cy).
__global__ __launch_bounds__(256) void gemm2_kernel(
    const float* __restrict__ h1u,    // (4096, 512) f32 FOLDED
    const int* __restrict__ idx,      // (P)
    const float* __restrict__ lxyz,   // (P, 3)
    const float* __restrict__ w1ls,   // [3][512] folded local weights
    const unsigned short* __restrict__ Bw,    // (512, 512) bf16
    float* __restrict__ sums,                 // BN2 stats
    float* __restrict__ pmax,                 // (4096, 512)
    float* __restrict__ pmin)
{
  __shared__ unsigned short As[2][128*32];
  __shared__ unsigned short Bs[2][128*32];
  __shared__ float wl[1536];
  int bx = blockIdx.x;
  int ob = bx & 3;
  size_t p0 = (size_t)(bx >> 2) * 128;
  int o0 = ob * 128;
  int t = threadIdx.x;
  int w = t >> 6, lane = t & 63;
  int wr = w >> 1, wc = w & 1;
  int l15 = lane & 15, l4 = lane >> 4;
  f32x4 acc[4][4];
  f32x4 zf = {0.f, 0.f, 0.f, 0.f};
  #pragma unroll
  for (int mi = 0; mi < 4; ++mi)
    #pragma unroll
    for (int ni = 0; ni < 4; ++ni) acc[mi][ni] = zf;

  int c0 = 2*w;
  int srow = lane >> 2;
  int scole = (lane & 3) * 8;

  #pragma unroll
  for (int e = 0; e < 6; ++e) wl[t + e*256] = w1ls[t + e*256];

  const float* hptr[2];
  const unsigned short* bptr[2];
  float lxr[2], lyr[2], lzr[2];
  #pragma unroll
  for (int cc = 0; cc < 2; ++cc) {
    int row = 16*(c0+cc) + srow;
    size_t p = p0 + row;
    int b = (int)(p >> 15);
    int n = idx[p];
    hptr[cc] = h1u + (((size_t)b << 10) + n)*512 + scole;
    const float* lwp = lxyz + p*3;
    lxr[cc] = lwp[0]; lyr[cc] = lwp[1]; lzr[cc] = lwp[2];
    bptr[cc] = Bw + (size_t)(o0 + row)*CIN + scole;
  }

  float4 hv0[2], hv1[2];

  // transform hv (tile data for k-block `kblk`) into As[buf]
  auto xform = [&](int kblk, int buf) {
    int ch0 = kblk + scole;
    float4 xa = *(const float4*)(wl + ch0);
    float4 xb = *(const float4*)(wl + ch0 + 4);
    float4 ya = *(const float4*)(wl + 512 + ch0);
    float4 yb = *(const float4*)(wl + 512 + ch0 + 4);
    float4 za = *(const float4*)(wl + 1024 + ch0);
    float4 zb = *(const float4*)(wl + 1024 + ch0 + 4);
    float w0[8] = {xa.x,xa.y,xa.z,xa.w,xb.x,xb.y,xb.z,xb.w};
    float w1[8] = {ya.x,ya.y,ya.z,ya.w,yb.x,yb.y,yb.z,yb.w};
    float w2[8] = {za.x,za.y,za.z,za.w,zb.x,zb.y,zb.z,zb.w};
    #pragma unroll
    for (int cc = 0; cc < 2; ++cc) {
      float fv[8] = {hv0[cc].x, hv0[cc].y, hv0[cc].z, hv0[cc].w,
                     hv1[cc].x, hv1[cc].y, hv1[cc].z, hv1[cc].w};
      float gv[8];
      #pragma unroll
      for (int e = 0; e < 8; ++e)
        gv[e] = fmaxf(fv[e] + lxr[cc]*w0[e] + lyr[cc]*w1[e] + lzr[cc]*w2[e], 0.f);
      unsigned int rv[4];
      #pragma unroll
      for (int j = 0; j < 4; ++j) rv[j] = cvtpk(gv[2*j], gv[2*j+1]);
      *(uint4*)((char*)&As[buf][0] + (c0+cc)*1024 + lane*16) = make_uint4(rv[0], rv[1], rv[2], rv[3]);
    }
  };

  // prologue: stage tile 0
  #pragma unroll
  for (int cc = 0; cc < 2; ++cc) {
    hv0[cc] = *(const float4*)(hptr[cc]);
    hv1[cc] = *(const float4*)(hptr[cc] + 4);
    load_lds16(bptr[cc], (char*)&Bs[0][0] + (c0+cc)*1024);
  }
  __syncthreads();                 // wl visible
  xform(0, 0);                     // As[0] <- tile 0
  #pragma unroll
  for (int cc = 0; cc < 2; ++cc) { // prefetch tile 1 A-data
    hv0[cc] = *(const float4*)(hptr[cc] + 32);
    hv1[cc] = *(const float4*)(hptr[cc] + 36);
  }
  __syncthreads();                 // As[0] writes + Bs[0] gloads complete

  int cur = 0;
  for (int kt = 0; kt < 16; ++kt) {
    int k0 = kt*32;
    if (kt < 15) {
      // stage tile kt+1 into buf^1 (issue loads first, then transform)
      #pragma unroll
      for (int cc = 0; cc < 2; ++cc)
        load_lds16(bptr[cc] + k0 + 32, (char*)&Bs[cur^1][0] + (c0+cc)*1024);
      xform(k0 + 32, cur^1);
      if (kt < 14) {
        #pragma unroll
        for (int cc = 0; cc < 2; ++cc) {   // prefetch tile kt+2 A-data
          hv0[cc] = *(const float4*)(hptr[cc] + k0 + 64);
          hv1[cc] = *(const float4*)(hptr[cc] + k0 + 68);
        }
      }
    }
    // compute tile kt from buf[cur]
    short8 af[4], bfr[4];
    #pragma unroll
    for (int mi = 0; mi < 4; ++mi)
      af[mi] = *(const short8*)(&As[cur][(wr*64 + mi*16 + l15)*32 + l4*8]);
    #pragma unroll
    for (int ni = 0; ni < 4; ++ni)
      bfr[ni] = *(const short8*)(&Bs[cur][(wc*64 + ni*16 + l15)*32 + l4*8]);
    #pragma unroll
    for (int mi = 0; mi < 4; ++mi)
      #pragma unroll
      for (int ni = 0; ni < 4; ++ni)
        acc[mi][ni] = __builtin_amdgcn_mfma_f32_16x16x32_bf16(af[mi], bfr[ni], acc[mi][ni], 0, 0, 0);
    __syncthreads();               // buf^1 fully staged; buf[cur] reads done
    cur ^= 1;
  }

  #pragma unroll
  for (int ni = 0; ni < 4; ++ni) {
    float s = 0.f, q = 0.f;
    #pragma unroll
    for (int mi = 0; mi < 4; ++mi)
      #pragma unroll
      for (int j = 0; j < 4; ++j) { float v = acc[mi][ni][j]; s += v; q += v*v; }
    s += __shfl_xor(s, 16); q += __shfl_xor(q, 16);
    s += __shfl_xor(s, 32); q += __shfl_xor(q, 32);
    if (l4 == 0) {
      int c = o0 + wc*64 + ni*16 + l15;
      atomicAdd(&sums[c], s);
      atomicAdd(&sums[512 + c], q);
    }
  }
  #pragma unroll
  for (int ni = 0; ni < 4; ++ni) {
    #pragma unroll
    for (int h = 0; h < 2; ++h) {
      float mx = -3.4e38f, mn = 3.4e38f;
      #pragma unroll
      for (int mi = 2*h; mi < 2*h + 2; ++mi)
        #pragma unroll
        for (int j = 0; j < 4; ++j) {
          float v = acc[mi][ni][j];
          mx = fmaxf(mx, v); mn = fminf(mn, v);
        }
      mx = fmaxf(mx, __shfl_xor(mx, 16)); mn = fminf(mn, __shfl_xor(mn, 16));
      mx = fmaxf(mx, __shfl_xor(mx, 32)); mn = fminf(mn, __shfl_xor(mn, 32));
      if (l4 == 0) {
        size_t bm = (p0 >> 5) + 2*wr + h;
        int o = o0 + wc*64 + ni*16 + l15;
        pmax[bm*512 + o] = mx;
        pmin[bm*512 + o] = mn;
      }
    }
  }
}

// ---------------- final: affine+relu on pooled, transpose to (B,512,M) ------
__global__ void final_transpose(const float* __restrict__ pmax,
                                const float* __restrict__ pmin,
                                const float* __restrict__ ss,
                                float* __restrict__ out) {
  __shared__ float tile[64][65];
  int b = blockIdx.z, ob = blockIdx.y, mb = blockIdx.x;
  int t = threadIdx.x, tr = t >> 6, tc = t & 63;
  #pragma unroll
  for (int j = 0; j < 16; ++j) {
    int m = mb*64 + j*4 + tr;
    int o = ob*64 + tc;
    float sc = ss[o], sh = ss[512+o];
    size_t pi = (((size_t)b << 10) + m)*512 + o;
    float v = (sc >= 0.f) ? pmax[pi] : pmin[pi];
    tile[j*4+tr][tc] = fmaxf(fmaf(v, sc, sh), 0.f);
  }
  __syncthreads();
  #pragma unroll
  for (int j = 0; j < 16; ++j) {
    int o = ob*64 + j*4 + tr;
    out[((size_t)b*512 + o)*1024 + mb*64 + tc] = tile[tc][j*4+tr];
  }
}

extern "C" void kernel_launch(void* const* d_in, const int* in_sizes, int n_in,
                              void* d_out, int out_size, void* d_ws, size_t ws_size,
                              hipStream_t stream) {
  const float* xyz   = (const float*)d_in[0];
  const float* feats = (const float*)d_in[1];
  const float* rot   = (const float*)d_in[2];
  const float* W1    = (const float*)d_in[3];
  const float* g1    = (const float*)d_in[4];
  const float* b1    = (const float*)d_in[5];
  const float* W2    = (const float*)d_in[6];
  const float* g2    = (const float*)d_in[7];
  const float* b2    = (const float*)d_in[8];
  float* out = (float*)d_out;
  char* wsb = (char*)d_ws;

  const size_t OFF_IDX    = 0;                                          // 512 KB
  const size_t OFF_LXYZ   = OFF_IDX    + (size_t)P_TOT*4;               // 1.5 MB
  const size_t OFF_FEATST = OFF_LXYZ   + (size_t)P_TOT*3*4;             // 4.2 MB
  const size_t OFF_W1F    = OFF_FEATST + (size_t)BATCH*NPTS*CIN*2;      // 512 KB
  const size_t OFF_W1L    = OFF_W1F    + (size_t)CO*512*2;              // 8 KB
  const size_t OFF_W1LS   = OFF_W1L    + 8192;                          // 8 KB
  const size_t OFF_W2B    = OFF_W1LS   + 8192;                          // 512 KB
  const size_t OFF_STATS  = OFF_W2B    + (size_t)CO*CIN*2;              // 16 KB
  const size_t OFF_L4     = OFF_STATS  + 16384;                         // 64 KB
  const size_t OFF_GM     = OFF_L4     + 65536;                         // 4 KB
  const size_t OFF_H1U    = OFF_GM     + 4096;                          // 8 MB
  const size_t OFF_PMAX   = OFF_H1U    + (size_t)BATCH*NPTS*CO*4;       // 8 MB
  const size_t OFF_PMIN   = OFF_PMAX   + (size_t)BATCH*NPTS*CO*4;       // 8 MB
  const size_t WS_NEED    = OFF_PMIN   + (size_t)BATCH*NPTS*CO*4;       // ~31 MiB

  if (ws_size < WS_NEED) return;   // diagnostic guard

  int* idx             = (int*)(wsb + OFF_IDX);
  float* lxyz          = (float*)(wsb + OFF_LXYZ);
  unsigned short* fT   = (unsigned short*)(wsb + OFF_FEATST);
  unsigned short* w1f  = (unsigned short*)(wsb + OFF_W1F);
  float* w1l           = (float*)(wsb + OFF_W1L);
  float* w1ls          = (float*)(wsb + OFF_W1LS);
  unsigned short* w2b  = (unsigned short*)(wsb + OFF_W2B);
  float* stats         = (float*)(wsb + OFF_STATS);
  float* sums1 = stats;
  float* ss1   = stats + 1024;
  float* sums2 = stats + 2048;
  float* ss2   = stats + 3072;
  float* L4            = (float*)(wsb + OFF_L4);
  float* GM            = (float*)(wsb + OFF_GM);
  float* h1u           = (float*)(wsb + OFF_H1U);
  float* pmax          = (float*)(wsb + OFF_PMAX);
  float* pmin          = (float*)(wsb + OFF_PMIN);

  hipMemsetAsync(stats, 0, 16384 + 65536 + 4096, stream);

  transpose_feats<<<dim3(NPTS/64, CIN/64, BATCH), 256, 0, stream>>>(feats, fT);
  cyl_query_kernel<<<BATCH*NPTS, 64, 0, stream>>>(xyz, rot, idx, lxyz);
  build_w1<<<(512*512 + 255)/256, 256, 0, stream>>>(W1, w1f, w1l);
  build_w2<<<(CO*CIN + 255)/256, 256, 0, stream>>>(W2, w2b);

  scatter_kernel<<<P_TOT/256, 256, 0, stream>>>(idx, lxyz, L4, GM);
  gemm1u_kernel<<<(BATCH*NPTS/128)*4, 256, 0, stream>>>(fT, w1f, h1u);
  stats1_kernel<<<256, 256, 0, stream>>>(h1u, L4, w1l, sums1);
  finalize1_kernel<<<2, 256, 0, stream>>>(sums1, GM, w1l, g1, b1, ss1, w1ls);
  fold_kernel<<<(BATCH*NPTS*CO/4)/256, 256, 0, stream>>>(h1u, ss1);

  gemm2_kernel<<<(P_TOT/128)*4, 256, 0, stream>>>(h1u, idx, lxyz, w1ls, w2b,
                                                  sums2, pmax, pmin);
  finalize_kernel<<<2, 256, 0, stream>>>(sums2, g2, b2, ss2);

  final_transpose<<<dim3(NPTS/64, CO/64, BATCH), 256, 0, stream>>>(pmax, pmin, ss2, out);
}

// Round 11
// 259.063 us; speedup vs baseline: 1.0540x; 1.0540x over previous
//
#include <hip/hip_runtime.h>
#include <hip/hip_bf16.h>
#include <stdint.h>

#define BATCH 4
#define NPTS  1024
#define CIN   512
#define NS    32
#define P_TOT (BATCH*NPTS*NS)      /* 131072 */
#define CO    512
#define RADIUS_F 0.05f
#define HMIN_F  (-0.02f)
#define HMAX_F  (0.04f)

typedef __attribute__((ext_vector_type(8))) short short8;
typedef __attribute__((ext_vector_type(4))) float f32x4;

__device__ __forceinline__ unsigned short f2bf(float f) {
  unsigned int x = __float_as_uint(f);
  x = x + 0x7fffu + ((x >> 16) & 1u);   // RNE
  return (unsigned short)(x >> 16);
}
__device__ __forceinline__ float bf2f(unsigned short u) {
  return __uint_as_float(((unsigned int)u) << 16);
}
__device__ __forceinline__ unsigned int cvtpk(float lo, float hi) {
  unsigned int r;
  asm("v_cvt_pk_bf16_f32 %0, %1, %2" : "=v"(r) : "v"(lo), "v"(hi));
  return r;   // D[15:0]=bf16(lo), D[31:16]=bf16(hi), RNE
}
__device__ __forceinline__ void load_lds16(const void* g, void* l) {
  __builtin_amdgcn_global_load_lds((const __attribute__((address_space(1))) void*)g,
                                   (__attribute__((address_space(3))) void*)l, 16, 0, 0);
}

// ---------------- cylinder query: idx + local coords (f32) ------------------
__global__ void cyl_query_kernel(const float* __restrict__ xyz,
                                 const float* __restrict__ rot,
                                 int* __restrict__ idxout,
                                 float* __restrict__ lxyz) {
  int bm = blockIdx.x;             // b*1024 + m
  int b = bm >> 10;
  int lane = threadIdx.x;          // 64 threads = 1 wave
  const float* ctr = xyz + (size_t)bm * 3;
  float cx = ctr[0], cy = ctr[1], cz = ctr[2];
  const float* R = rot + (size_t)bm * 9;
  float r00=R[0],r01=R[1],r02=R[2],r10=R[3],r11=R[4],r12=R[5],r20=R[6],r21=R[7],r22=R[8];
  __shared__ int sidx[32];
  int taken = 0;
  for (int base = 0; base < NPTS && taken < NS; base += 64) {
    int n = base + lane;
    const float* p = xyz + ((size_t)b * NPTS + n) * 3;
    float dx = p[0]-cx, dy = p[1]-cy, dz = p[2]-cz;
    float rx = dx*r00 + dy*r10 + dz*r20;
    float ry = dx*r01 + dy*r11 + dz*r21;
    float rz = dx*r02 + dy*r12 + dz*r22;
    bool ok = (ry*ry + rz*rz < RADIUS_F*RADIUS_F) && (rx > HMIN_F) && (rx < HMAX_F);
    unsigned long long bal = __ballot(ok);
    if (ok) {
      int slot = taken + __popcll(bal & ((1ull << lane) - 1ull));
      if (slot < NS) sidx[slot] = n;
    }
    taken += __popcll(bal);
  }
  __syncthreads();
  int filled = taken < NS ? taken : NS;
  if (lane < NS) {
    int nsel = (lane < filled) ? sidx[lane] : sidx[0];
    size_t pp = (size_t)bm * NS + lane;
    idxout[pp] = nsel;
    const float* pn = xyz + ((size_t)b * NPTS + nsel) * 3;
    float dx = pn[0]-cx, dy = pn[1]-cy, dz = pn[2]-cz;
    const float inv = 1.0f / RADIUS_F;
    float rx = (dx*r00 + dy*r10 + dz*r20) * inv;
    float ry = (dx*r01 + dy*r11 + dz*r21) * inv;
    float rz = (dx*r02 + dy*r12 + dz*r22) * inv;
    float* lw = lxyz + pp * 3;
    lw[0] = rx; lw[1] = ry; lw[2] = rz;
  }
}

// ---------------- transpose feats (B,C,N) fp32 -> (B,N,C) bf16 --------------
__global__ void transpose_feats(const float* __restrict__ feats,
                                unsigned short* __restrict__ featsT) {
  __shared__ float tile[64][65];
  int b = blockIdx.z, cb = blockIdx.y, nb = blockIdx.x;
  int t = threadIdx.x, tr = t >> 6, tc = t & 63;
  #pragma unroll
  for (int j = 0; j < 16; ++j) {
    int c = cb*64 + j*4 + tr;
    tile[j*4+tr][tc] = feats[((size_t)b*CIN + c)*NPTS + nb*64 + tc];
  }
  __syncthreads();
  #pragma unroll
  for (int j = 0; j < 16; ++j) {
    int n = nb*64 + j*4 + tr;
    featsT[((size_t)b*NPTS + n)*CIN + cb*64 + tc] = f2bf(tile[tc][j*4+tr]);
  }
}

// ---------------- weight conversion -----------------------------------------
__global__ void build_w1(const float* __restrict__ W1,
                         unsigned short* __restrict__ w1f,
                         float* __restrict__ w1l) {
  int i = blockIdx.x*256 + threadIdx.x;
  if (i < 512*512) {
    int o = i >> 9, k = i & 511;
    w1f[i] = f2bf(W1[o*515 + 3 + k]);
  }
  if (i < 512*3) {
    w1l[i] = W1[(i/3)*515 + (i%3)];
  }
}
__global__ void build_w2(const float* __restrict__ W2, unsigned short* __restrict__ w2b) {
  int i = blockIdx.x*256 + threadIdx.x;
  if (i < CO*CIN) w2b[i] = f2bf(W2[i]);
}

// ============ scatter: per-unique-row local sums + counts + global moments ===
__global__ __launch_bounds__(256) void scatter_kernel(
    const int* __restrict__ idx, const float* __restrict__ lxyz,
    float* __restrict__ L4, float* __restrict__ GM) {
  int i = blockIdx.x*256 + threadIdx.x;   // 512 blocks x 256 = P_TOT
  int b = i >> 15;
  int n = idx[i];
  const float* lw = lxyz + (size_t)i*3;
  float lx = lw[0], ly = lw[1], lz = lw[2];
  float* dst = L4 + (((size_t)b << 10) + n)*4;
  atomicAdd(dst+0, lx); atomicAdd(dst+1, ly);
  atomicAdd(dst+2, lz); atomicAdd(dst+3, 1.0f);
  float m[9] = {lx, ly, lz, lx*lx, lx*ly, lx*lz, ly*ly, ly*lz, lz*lz};
  #pragma unroll
  for (int d = 1; d < 64; d <<= 1)
    #pragma unroll
    for (int e = 0; e < 9; ++e) m[e] += __shfl_xor(m[e], d);
  __shared__ float mred[9];
  if (threadIdx.x < 9) mred[threadIdx.x] = 0.f;
  __syncthreads();
  if ((threadIdx.x & 63) == 0)
    #pragma unroll
    for (int e = 0; e < 9; ++e) atomicAdd(&mred[e], m[e]);
  __syncthreads();
  if (threadIdx.x < 9) atomicAdd(&GM[threadIdx.x], mred[threadIdx.x]);
}

// ============ GEMM1u: unique-point features x W1f^T (fp32 out) ==============
__global__ __launch_bounds__(256) void gemm1u_kernel(
    const unsigned short* __restrict__ A,
    const unsigned short* __restrict__ Bw,
    float* __restrict__ C)
{
  __shared__ unsigned short As[128*32];
  __shared__ unsigned short Bs[128*32];
  int bx = blockIdx.x;
  int ob = bx & 3;
  size_t p0 = (size_t)(bx >> 2) * 128;
  int o0 = ob * 128;
  int t = threadIdx.x;
  int w = t >> 6, lane = t & 63;
  int wr = w >> 1, wc = w & 1;
  int l15 = lane & 15, l4 = lane >> 4;
  f32x4 acc[4][4];
  f32x4 zf = {0.f, 0.f, 0.f, 0.f};
  #pragma unroll
  for (int mi = 0; mi < 4; ++mi)
    #pragma unroll
    for (int ni = 0; ni < 4; ++ni) acc[mi][ni] = zf;

  int c0 = 2*w;
  int srow = lane >> 2;
  int scole = (lane & 3) * 8;

  const unsigned short* abase[2];
  const unsigned short* bbase[2];
  #pragma unroll
  for (int cc = 0; cc < 2; ++cc) {
    int row = 16*(c0+cc) + srow;
    abase[cc] = A + (p0 + row)*(size_t)512 + scole;
    bbase[cc] = Bw + (size_t)(o0 + row)*512 + scole;
  }

  for (int k0 = 0; k0 < 512; k0 += 32) {
    #pragma unroll
    for (int cc = 0; cc < 2; ++cc) {
      int c = c0 + cc;
      load_lds16(abase[cc] + k0, (char*)As + c*1024);
      load_lds16(bbase[cc] + k0, (char*)Bs + c*1024);
    }
    __syncthreads();
    short8 af[4], bfr[4];
    #pragma unroll
    for (int mi = 0; mi < 4; ++mi)
      af[mi] = *(const short8*)(As + (wr*64 + mi*16 + l15)*32 + l4*8);
    #pragma unroll
    for (int ni = 0; ni < 4; ++ni)
      bfr[ni] = *(const short8*)(Bs + (wc*64 + ni*16 + l15)*32 + l4*8);
    #pragma unroll
    for (int mi = 0; mi < 4; ++mi)
      #pragma unroll
      for (int ni = 0; ni < 4; ++ni)
        acc[mi][ni] = __builtin_amdgcn_mfma_f32_16x16x32_bf16(af[mi], bfr[ni], acc[mi][ni], 0, 0, 0);
    __syncthreads();
  }
  #pragma unroll
  for (int mi = 0; mi < 4; ++mi)
    #pragma unroll
    for (int ni = 0; ni < 4; ++ni)
      #pragma unroll
      for (int j = 0; j < 4; ++j) {
        size_t p = p0 + wr*64 + mi*16 + l4*4 + j;
        int o = o0 + wc*64 + ni*16 + l15;
        C[p*512 + o] = acc[mi][ni][j];
      }
}

// ============ stats1: algebraic BN1 sums over u (one h1u read) ==============
__global__ __launch_bounds__(256) void stats1_kernel(
    const float* __restrict__ h1u, const float* __restrict__ L4,
    const float* __restrict__ w1l, float* __restrict__ sums) {
  int t = threadIdx.x;
  int c2 = t*2;
  int u0 = blockIdx.x * 16;
  float w0a = w1l[c2*3],     w1a = w1l[c2*3+1],     w2a = w1l[c2*3+2];
  float w0b = w1l[(c2+1)*3], w1b = w1l[(c2+1)*3+1], w2b = w1l[(c2+1)*3+2];
  float s0=0.f, s1=0.f, q0=0.f, q1=0.f;
  #pragma unroll 4
  for (int j = 0; j < 16; ++j) {
    int u = u0 + j;
    float4 Lc = *(const float4*)(L4 + (size_t)u*4);
    float2 h = *(const float2*)(h1u + (size_t)u*512 + c2);
    float lwa = Lc.x*w0a + Lc.y*w1a + Lc.z*w2a;
    float lwb = Lc.x*w0b + Lc.y*w1b + Lc.z*w2b;
    s0 += Lc.w*h.x;  q0 += Lc.w*h.x*h.x + 2.f*h.x*lwa;
    s1 += Lc.w*h.y;  q1 += Lc.w*h.y*h.y + 2.f*h.y*lwb;
  }
  atomicAdd(&sums[c2],       s0);
  atomicAdd(&sums[c2+1],     s1);
  atomicAdd(&sums[512+c2],   q0);
  atomicAdd(&sums[512+c2+1], q1);
}

// ---- finalize1: BN1 scale/shift + folded local weights w1ls = sc*w1l -------
__global__ void finalize1_kernel(const float* __restrict__ sums,
                                 const float* __restrict__ GM,
                                 const float* __restrict__ w1l,
                                 const float* __restrict__ g,
                                 const float* __restrict__ bia,
                                 float* __restrict__ ss,
                                 float* __restrict__ w1ls) {
  int c = blockIdx.x*256 + threadIdx.x;
  if (c >= 512) return;
  float w0 = w1l[c*3], w1 = w1l[c*3+1], w2 = w1l[c*3+2];
  float S = sums[c] + w0*GM[0] + w1*GM[1] + w2*GM[2];
  float Q = sums[512+c] + w0*w0*GM[3] + 2.f*w0*w1*GM[4] + 2.f*w0*w2*GM[5]
                        + w1*w1*GM[6] + 2.f*w1*w2*GM[7] + w2*w2*GM[8];
  const float invN = 1.f / (float)P_TOT;
  float mean = S * invN;
  float var  = Q * invN - mean*mean;
  float sc = g[c] * rsqrtf(var + 1e-5f);
  ss[c] = sc;
  ss[512+c] = bia[c] - mean*sc;
  w1ls[c]        = sc * w0;   // planar [3][512]
  w1ls[512 + c]  = sc * w1;
  w1ls[1024 + c] = sc * w2;
}

// ---- fold: h1u <- sc*h1u + sh (in place; BN1 affine folded into operand) ---
__global__ __launch_bounds__(256) void fold_kernel(float* __restrict__ h1u,
                                                   const float* __restrict__ ss) {
  size_t i = ((size_t)blockIdx.x*256 + threadIdx.x) * 4;   // 2048 blocks
  int c = (int)(i & 511);
  float4 v = *(float4*)(h1u + i);
  float4 sc = *(const float4*)(ss + c);
  float4 sh = *(const float4*)(ss + 512 + c);
  v.x = fmaf(v.x, sc.x, sh.x);
  v.y = fmaf(v.y, sc.y, sh.y);
  v.z = fmaf(v.z, sc.z, sh.z);
  v.w = fmaf(v.w, sc.w, sh.w);
  *(float4*)(h1u + i) = v;
}

__global__ void finalize_kernel(const float* __restrict__ sums,
                                const float* __restrict__ g,
                                const float* __restrict__ bia,
                                float* __restrict__ ss) {
  int c = blockIdx.x*256 + threadIdx.x;
  if (c >= 512) return;
  const float invN = 1.f / (float)P_TOT;
  float mean = sums[c] * invN;
  float var  = sums[512+c] * invN - mean*mean;
  float sc = g[c] * rsqrtf(var + 1e-5f);
  ss[c] = sc;
  ss[512+c] = bia[c] - mean*sc;
}

// ============ GEMM2 v4: r9 loop + slot-XOR LDS swizzle (T2, rule-21) ========
// A = relu(h1u'[u] + l·w1ls) -> bf16. Single-buffer 2-barrier loop (r9).
// Swizzle: LDS[row][s] = G[row][s ^ ((row>>1)&3)] (16B slots, 4/row).
//   Bs: pre-swizzled GLOBAL source + linear gload_lds dest.
//   As: swizzled ds_write dest (data unchanged).
//   reads: slot = l4 ^ ((l15>>1)&3)  (row-XOR reduces: bases 16-aligned).
__global__ __launch_bounds__(256) void gemm2_kernel(
    const float* __restrict__ h1u,    // (4096, 512) f32 FOLDED
    const int* __restrict__ idx,      // (P)
    const float* __restrict__ lxyz,   // (P, 3)
    const float* __restrict__ w1ls,   // [3][512] folded local weights
    const unsigned short* __restrict__ Bw,    // (512, 512) bf16
    float* __restrict__ sums,                 // BN2 stats
    float* __restrict__ pmax,                 // (4096, 512)
    float* __restrict__ pmin)
{
  __shared__ unsigned short As[128*32];
  __shared__ unsigned short Bs[128*32];
  __shared__ float wl[1536];
  int bx = blockIdx.x;
  int ob = bx & 3;
  size_t p0 = (size_t)(bx >> 2) * 128;
  int o0 = ob * 128;
  int t = threadIdx.x;
  int w = t >> 6, lane = t & 63;
  int wr = w >> 1, wc = w & 1;
  int l15 = lane & 15, l4 = lane >> 4;
  f32x4 acc[4][4];
  f32x4 zf = {0.f, 0.f, 0.f, 0.f};
  #pragma unroll
  for (int mi = 0; mi < 4; ++mi)
    #pragma unroll
    for (int ni = 0; ni < 4; ++ni) acc[mi][ni] = zf;

  int c0 = 2*w;
  int srow = lane >> 2;
  int scole = (lane & 3) * 8;
  int sl = (lane & 3) ^ ((lane >> 3) & 3);       // swizzled 16B slot
  int awoff = (lane >> 2)*64 + sl*16;            // As write byte offset in chunk
  int cA = (l4 ^ ((l15 >> 1) & 3)) * 8;          // swizzled read elem offset

  #pragma unroll
  for (int e = 0; e < 6; ++e) wl[t + e*256] = w1ls[t + e*256];

  const float* hptr[2];
  const unsigned short* bptr[2];
  float lxr[2], lyr[2], lzr[2];
  #pragma unroll
  for (int cc = 0; cc < 2; ++cc) {
    int row = 16*(c0+cc) + srow;
    size_t p = p0 + row;
    int b = (int)(p >> 15);
    int n = idx[p];
    hptr[cc] = h1u + (((size_t)b << 10) + n)*512 + scole;
    const float* lwp = lxyz + p*3;
    lxr[cc] = lwp[0]; lyr[cc] = lwp[1]; lzr[cc] = lwp[2];
    bptr[cc] = Bw + (size_t)(o0 + row)*CIN + sl*8;   // pre-swizzled source
  }

  float4 hv0[2], hv1[2];
  #pragma unroll
  for (int cc = 0; cc < 2; ++cc) {
    hv0[cc] = *(const float4*)(hptr[cc]);
    hv1[cc] = *(const float4*)(hptr[cc] + 4);
  }
  __syncthreads();   // wl staged

  for (int k0 = 0; k0 < CIN; k0 += 32) {
    #pragma unroll
    for (int cc = 0; cc < 2; ++cc)
      load_lds16(bptr[cc] + k0, (char*)Bs + (c0+cc)*1024);   // linear dest
    // folded local-weight tables for channels k0+scole..+7 (b128 reads)
    int ch0 = k0 + scole;
    float4 xa = *(const float4*)(wl + ch0);
    float4 xb = *(const float4*)(wl + ch0 + 4);
    float4 ya = *(const float4*)(wl + 512 + ch0);
    float4 yb = *(const float4*)(wl + 512 + ch0 + 4);
    float4 za = *(const float4*)(wl + 1024 + ch0);
    float4 zb = *(const float4*)(wl + 1024 + ch0 + 4);
    float w0[8] = {xa.x,xa.y,xa.z,xa.w,xb.x,xb.y,xb.z,xb.w};
    float w1[8] = {ya.x,ya.y,ya.z,ya.w,yb.x,yb.y,yb.z,yb.w};
    float w2[8] = {za.x,za.y,za.z,za.w,zb.x,zb.y,zb.z,zb.w};
    #pragma unroll
    for (int cc = 0; cc < 2; ++cc) {
      float fv[8] = {hv0[cc].x, hv0[cc].y, hv0[cc].z, hv0[cc].w,
                     hv1[cc].x, hv1[cc].y, hv1[cc].z, hv1[cc].w};
      float gv[8];
      #pragma unroll
      for (int e = 0; e < 8; ++e)
        gv[e] = fmaxf(fv[e] + lxr[cc]*w0[e] + lyr[cc]*w1[e] + lzr[cc]*w2[e], 0.f);
      unsigned int rv[4];
      #pragma unroll
      for (int j = 0; j < 4; ++j) rv[j] = cvtpk(gv[2*j], gv[2*j+1]);
      *(uint4*)((char*)As + (c0+cc)*1024 + awoff) = make_uint4(rv[0], rv[1], rv[2], rv[3]);
    }
    if (k0 + 32 < CIN) {
      #pragma unroll
      for (int cc = 0; cc < 2; ++cc) {
        hv0[cc] = *(const float4*)(hptr[cc] + k0 + 32);
        hv1[cc] = *(const float4*)(hptr[cc] + k0 + 36);
      }
    }
    __syncthreads();
    short8 af[4], bfr[4];
    #pragma unroll
    for (int mi = 0; mi < 4; ++mi)
      af[mi] = *(const short8*)(As + (wr*64 + mi*16 + l15)*32 + cA);
    #pragma unroll
    for (int ni = 0; ni < 4; ++ni)
      bfr[ni] = *(const short8*)(Bs + (wc*64 + ni*16 + l15)*32 + cA);
    #pragma unroll
    for (int mi = 0; mi < 4; ++mi)
      #pragma unroll
      for (int ni = 0; ni < 4; ++ni)
        acc[mi][ni] = __builtin_amdgcn_mfma_f32_16x16x32_bf16(af[mi], bfr[ni], acc[mi][ni], 0, 0, 0);
    __syncthreads();
  }

  #pragma unroll
  for (int ni = 0; ni < 4; ++ni) {
    float s = 0.f, q = 0.f;
    #pragma unroll
    for (int mi = 0; mi < 4; ++mi)
      #pragma unroll
      for (int j = 0; j < 4; ++j) { float v = acc[mi][ni][j]; s += v; q += v*v; }
    s += __shfl_xor(s, 16); q += __shfl_xor(q, 16);
    s += __shfl_xor(s, 32); q += __shfl_xor(q, 32);
    if (l4 == 0) {
      int c = o0 + wc*64 + ni*16 + l15;
      atomicAdd(&sums[c], s);
      atomicAdd(&sums[512 + c], q);
    }
  }
  #pragma unroll
  for (int ni = 0; ni < 4; ++ni) {
    #pragma unroll
    for (int h = 0; h < 2; ++h) {
      float mx = -3.4e38f, mn = 3.4e38f;
      #pragma unroll
      for (int mi = 2*h; mi < 2*h + 2; ++mi)
        #pragma unroll
        for (int j = 0; j < 4; ++j) {
          float v = acc[mi][ni][j];
          mx = fmaxf(mx, v); mn = fminf(mn, v);
        }
      mx = fmaxf(mx, __shfl_xor(mx, 16)); mn = fminf(mn, __shfl_xor(mn, 16));
      mx = fmaxf(mx, __shfl_xor(mx, 32)); mn = fminf(mn, __shfl_xor(mn, 32));
      if (l4 == 0) {
        size_t bm = (p0 >> 5) + 2*wr + h;
        int o = o0 + wc*64 + ni*16 + l15;
        pmax[bm*512 + o] = mx;
        pmin[bm*512 + o] = mn;
      }
    }
  }
}

// ---------------- final: affine+relu on pooled, transpose to (B,512,M) ------
__global__ void final_transpose(const float* __restrict__ pmax,
                                const float* __restrict__ pmin,
                                const float* __restrict__ ss,
                                float* __restrict__ out) {
  __shared__ float tile[64][65];
  int b = blockIdx.z, ob = blockIdx.y, mb = blockIdx.x;
  int t = threadIdx.x, tr = t >> 6, tc = t & 63;
  #pragma unroll
  for (int j = 0; j < 16; ++j) {
    int m = mb*64 + j*4 + tr;
    int o = ob*64 + tc;
    float sc = ss[o], sh = ss[512+o];
    size_t pi = (((size_t)b << 10) + m)*512 + o;
    float v = (sc >= 0.f) ? pmax[pi] : pmin[pi];
    tile[j*4+tr][tc] = fmaxf(fmaf(v, sc, sh), 0.f);
  }
  __syncthreads();
  #pragma unroll
  for (int j = 0; j < 16; ++j) {
    int o = ob*64 + j*4 + tr;
    out[((size_t)b*512 + o)*1024 + mb*64 + tc] = tile[tc][j*4+tr];
  }
}

extern "C" void kernel_launch(void* const* d_in, const int* in_sizes, int n_in,
                              void* d_out, int out_size, void* d_ws, size_t ws_size,
                              hipStream_t stream) {
  const float* xyz   = (const float*)d_in[0];
  const float* feats = (const float*)d_in[1];
  const float* rot   = (const float*)d_in[2];
  const float* W1    = (const float*)d_in[3];
  const float* g1    = (const float*)d_in[4];
  const float* b1    = (const float*)d_in[5];
  const float* W2    = (const float*)d_in[6];
  const float* g2    = (const float*)d_in[7];
  const float* b2    = (const float*)d_in[8];
  float* out = (float*)d_out;
  char* wsb = (char*)d_ws;

  const size_t OFF_IDX    = 0;                                          // 512 KB
  const size_t OFF_LXYZ   = OFF_IDX    + (size_t)P_TOT*4;               // 1.5 MB
  const size_t OFF_FEATST = OFF_LXYZ   + (size_t)P_TOT*3*4;             // 4.2 MB
  const size_t OFF_W1F    = OFF_FEATST + (size_t)BATCH*NPTS*CIN*2;      // 512 KB
  const size_t OFF_W1L    = OFF_W1F    + (size_t)CO*512*2;              // 8 KB
  const size_t OFF_W1LS   = OFF_W1L    + 8192;                          // 8 KB
  const size_t OFF_W2B    = OFF_W1LS   + 8192;                          // 512 KB
  const size_t OFF_STATS  = OFF_W2B    + (size_t)CO*CIN*2;              // 16 KB
  const size_t OFF_L4     = OFF_STATS  + 16384;                         // 64 KB
  const size_t OFF_GM     = OFF_L4     + 65536;                         // 4 KB
  const size_t OFF_H1U    = OFF_GM     + 4096;                          // 8 MB
  const size_t OFF_PMAX   = OFF_H1U    + (size_t)BATCH*NPTS*CO*4;       // 8 MB
  const size_t OFF_PMIN   = OFF_PMAX   + (size_t)BATCH*NPTS*CO*4;       // 8 MB
  const size_t WS_NEED    = OFF_PMIN   + (size_t)BATCH*NPTS*CO*4;       // ~31 MiB

  if (ws_size < WS_NEED) return;   // diagnostic guard

  int* idx             = (int*)(wsb + OFF_IDX);
  float* lxyz          = (float*)(wsb + OFF_LXYZ);
  unsigned short* fT   = (unsigned short*)(wsb + OFF_FEATST);
  unsigned short* w1f  = (unsigned short*)(wsb + OFF_W1F);
  float* w1l           = (float*)(wsb + OFF_W1L);
  float* w1ls          = (float*)(wsb + OFF_W1LS);
  unsigned short* w2b  = (unsigned short*)(wsb + OFF_W2B);
  float* stats         = (float*)(wsb + OFF_STATS);
  float* sums1 = stats;
  float* ss1   = stats + 1024;
  float* sums2 = stats + 2048;
  float* ss2   = stats + 3072;
  float* L4            = (float*)(wsb + OFF_L4);
  float* GM            = (float*)(wsb + OFF_GM);
  float* h1u           = (float*)(wsb + OFF_H1U);
  float* pmax          = (float*)(wsb + OFF_PMAX);
  float* pmin          = (float*)(wsb + OFF_PMIN);

  hipMemsetAsync(stats, 0, 16384 + 65536 + 4096, stream);

  transpose_feats<<<dim3(NPTS/64, CIN/64, BATCH), 256, 0, stream>>>(feats, fT);
  cyl_query_kernel<<<BATCH*NPTS, 64, 0, stream>>>(xyz, rot, idx, lxyz);
  build_w1<<<(512*512 + 255)/256, 256, 0, stream>>>(W1, w1f, w1l);
  build_w2<<<(CO*CIN + 255)/256, 256, 0, stream>>>(W2, w2b);

  scatter_kernel<<<P_TOT/256, 256, 0, stream>>>(idx, lxyz, L4, GM);
  gemm1u_kernel<<<(BATCH*NPTS/128)*4, 256, 0, stream>>>(fT, w1f, h1u);
  stats1_kernel<<<256, 256, 0, stream>>>(h1u, L4, w1l, sums1);
  finalize1_kernel<<<2, 256, 0, stream>>>(sums1, GM, w1l, g1, b1, ss1, w1ls);
  fold_kernel<<<(BATCH*NPTS*CO/4)/256, 256, 0, stream>>>(h1u, ss1);

  gemm2_kernel<<<(P_TOT/128)*4, 256, 0, stream>>>(h1u, idx, lxyz, w1ls, w2b,
                                                  sums2, pmax, pmin);
  finalize_kernel<<<2, 256, 0, stream>>>(sums2, g2, b2, ss2);

  final_transpose<<<dim3(NPTS/64, CO/64, BATCH), 256, 0, stream>>>(pmax, pmin, ss2, out);
}

// Round 12
// 216.165 us; speedup vs baseline: 1.2631x; 1.1984x over previous
//
#include <hip/hip_runtime.h>
#include <hip/hip_bf16.h>
#include <stdint.h>

#define BATCH 4
#define NPTS  1024
#define CIN   512
#define NS    32
#define P_TOT (BATCH*NPTS*NS)      /* 131072 */
#define CO    512
#define RADIUS_F 0.05f
#define HMIN_F  (-0.02f)
#define HMAX_F  (0.04f)

typedef __attribute__((ext_vector_type(8))) short short8;
typedef __attribute__((ext_vector_type(4))) float f32x4;

__device__ __forceinline__ unsigned short f2bf(float f) {
  unsigned int x = __float_as_uint(f);
  x = x + 0x7fffu + ((x >> 16) & 1u);   // RNE
  return (unsigned short)(x >> 16);
}
__device__ __forceinline__ float bf2f(unsigned short u) {
  return __uint_as_float(((unsigned int)u) << 16);
}
__device__ __forceinline__ unsigned int cvtpk(float lo, float hi) {
  unsigned int r;
  asm("v_cvt_pk_bf16_f32 %0, %1, %2" : "=v"(r) : "v"(lo), "v"(hi));
  return r;   // D[15:0]=bf16(lo), D[31:16]=bf16(hi), RNE
}
__device__ __forceinline__ void load_lds16(const void* g, void* l) {
  __builtin_amdgcn_global_load_lds((const __attribute__((address_space(1))) void*)g,
                                   (__attribute__((address_space(3))) void*)l, 16, 0, 0);
}

// ---------------- cylinder query: idx + local coords (f32) ------------------
__global__ void cyl_query_kernel(const float* __restrict__ xyz,
                                 const float* __restrict__ rot,
                                 int* __restrict__ idxout,
                                 float* __restrict__ lxyz) {
  int bm = blockIdx.x;             // b*1024 + m
  int b = bm >> 10;
  int lane = threadIdx.x;          // 64 threads = 1 wave
  const float* ctr = xyz + (size_t)bm * 3;
  float cx = ctr[0], cy = ctr[1], cz = ctr[2];
  const float* R = rot + (size_t)bm * 9;
  float r00=R[0],r01=R[1],r02=R[2],r10=R[3],r11=R[4],r12=R[5],r20=R[6],r21=R[7],r22=R[8];
  __shared__ int sidx[32];
  int taken = 0;
  for (int base = 0; base < NPTS && taken < NS; base += 64) {
    int n = base + lane;
    const float* p = xyz + ((size_t)b * NPTS + n) * 3;
    float dx = p[0]-cx, dy = p[1]-cy, dz = p[2]-cz;
    float rx = dx*r00 + dy*r10 + dz*r20;
    float ry = dx*r01 + dy*r11 + dz*r21;
    float rz = dx*r02 + dy*r12 + dz*r22;
    bool ok = (ry*ry + rz*rz < RADIUS_F*RADIUS_F) && (rx > HMIN_F) && (rx < HMAX_F);
    unsigned long long bal = __ballot(ok);
    if (ok) {
      int slot = taken + __popcll(bal & ((1ull << lane) - 1ull));
      if (slot < NS) sidx[slot] = n;
    }
    taken += __popcll(bal);
  }
  __syncthreads();
  int filled = taken < NS ? taken : NS;
  if (lane < NS) {
    int nsel = (lane < filled) ? sidx[lane] : sidx[0];
    size_t pp = (size_t)bm * NS + lane;
    idxout[pp] = nsel;
    const float* pn = xyz + ((size_t)b * NPTS + nsel) * 3;
    float dx = pn[0]-cx, dy = pn[1]-cy, dz = pn[2]-cz;
    const float inv = 1.0f / RADIUS_F;
    float rx = (dx*r00 + dy*r10 + dz*r20) * inv;
    float ry = (dx*r01 + dy*r11 + dz*r21) * inv;
    float rz = (dx*r02 + dy*r12 + dz*r22) * inv;
    float* lw = lxyz + pp * 3;
    lw[0] = rx; lw[1] = ry; lw[2] = rz;
  }
}

// ---------------- transpose feats (B,C,N) fp32 -> (B,N,C) bf16 --------------
__global__ void transpose_feats(const float* __restrict__ feats,
                                unsigned short* __restrict__ featsT) {
  __shared__ float tile[64][65];
  int b = blockIdx.z, cb = blockIdx.y, nb = blockIdx.x;
  int t = threadIdx.x, tr = t >> 6, tc = t & 63;
  #pragma unroll
  for (int j = 0; j < 16; ++j) {
    int c = cb*64 + j*4 + tr;
    tile[j*4+tr][tc] = feats[((size_t)b*CIN + c)*NPTS + nb*64 + tc];
  }
  __syncthreads();
  #pragma unroll
  for (int j = 0; j < 16; ++j) {
    int n = nb*64 + j*4 + tr;
    featsT[((size_t)b*NPTS + n)*CIN + cb*64 + tc] = f2bf(tile[tc][j*4+tr]);
  }
}

// ---------------- weight conversion -----------------------------------------
__global__ void build_w1(const float* __restrict__ W1,
                         unsigned short* __restrict__ w1f,
                         float* __restrict__ w1l) {
  int i = blockIdx.x*256 + threadIdx.x;
  if (i < 512*512) {
    int o = i >> 9, k = i & 511;
    w1f[i] = f2bf(W1[o*515 + 3 + k]);
  }
  if (i < 512*3) {
    w1l[i] = W1[(i/3)*515 + (i%3)];
  }
}
__global__ void build_w2(const float* __restrict__ W2, unsigned short* __restrict__ w2b) {
  int i = blockIdx.x*256 + threadIdx.x;
  if (i < CO*CIN) w2b[i] = f2bf(W2[i]);
}

// ============ scatter: per-unique-row local sums + counts + global moments ===
__global__ __launch_bounds__(256) void scatter_kernel(
    const int* __restrict__ idx, const float* __restrict__ lxyz,
    float* __restrict__ L4, float* __restrict__ GM) {
  int i = blockIdx.x*256 + threadIdx.x;   // 512 blocks x 256 = P_TOT
  int b = i >> 15;
  int n = idx[i];
  const float* lw = lxyz + (size_t)i*3;
  float lx = lw[0], ly = lw[1], lz = lw[2];
  float* dst = L4 + (((size_t)b << 10) + n)*4;
  atomicAdd(dst+0, lx); atomicAdd(dst+1, ly);
  atomicAdd(dst+2, lz); atomicAdd(dst+3, 1.0f);
  float m[9] = {lx, ly, lz, lx*lx, lx*ly, lx*lz, ly*ly, ly*lz, lz*lz};
  #pragma unroll
  for (int d = 1; d < 64; d <<= 1)
    #pragma unroll
    for (int e = 0; e < 9; ++e) m[e] += __shfl_xor(m[e], d);
  __shared__ float mred[9];
  if (threadIdx.x < 9) mred[threadIdx.x] = 0.f;
  __syncthreads();
  if ((threadIdx.x & 63) == 0)
    #pragma unroll
    for (int e = 0; e < 9; ++e) atomicAdd(&mred[e], m[e]);
  __syncthreads();
  if (threadIdx.x < 9) atomicAdd(&GM[threadIdx.x], mred[threadIdx.x]);
}

// ============ GEMM1u: unique-point features x W1f^T (fp32 out) ==============
__global__ __launch_bounds__(256) void gemm1u_kernel(
    const unsigned short* __restrict__ A,
    const unsigned short* __restrict__ Bw,
    float* __restrict__ C)
{
  __shared__ unsigned short As[128*32];
  __shared__ unsigned short Bs[128*32];
  int bx = blockIdx.x;
  int ob = bx & 3;
  size_t p0 = (size_t)(bx >> 2) * 128;
  int o0 = ob * 128;
  int t = threadIdx.x;
  int w = t >> 6, lane = t & 63;
  int wr = w >> 1, wc = w & 1;
  int l15 = lane & 15, l4 = lane >> 4;
  f32x4 acc[4][4];
  f32x4 zf = {0.f, 0.f, 0.f, 0.f};
  #pragma unroll
  for (int mi = 0; mi < 4; ++mi)
    #pragma unroll
    for (int ni = 0; ni < 4; ++ni) acc[mi][ni] = zf;

  int c0 = 2*w;
  int srow = lane >> 2;
  int scole = (lane & 3) * 8;

  const unsigned short* abase[2];
  const unsigned short* bbase[2];
  #pragma unroll
  for (int cc = 0; cc < 2; ++cc) {
    int row = 16*(c0+cc) + srow;
    abase[cc] = A + (p0 + row)*(size_t)512 + scole;
    bbase[cc] = Bw + (size_t)(o0 + row)*512 + scole;
  }

  for (int k0 = 0; k0 < 512; k0 += 32) {
    #pragma unroll
    for (int cc = 0; cc < 2; ++cc) {
      int c = c0 + cc;
      load_lds16(abase[cc] + k0, (char*)As + c*1024);
      load_lds16(bbase[cc] + k0, (char*)Bs + c*1024);
    }
    __syncthreads();
    short8 af[4], bfr[4];
    #pragma unroll
    for (int mi = 0; mi < 4; ++mi)
      af[mi] = *(const short8*)(As + (wr*64 + mi*16 + l15)*32 + l4*8);
    #pragma unroll
    for (int ni = 0; ni < 4; ++ni)
      bfr[ni] = *(const short8*)(Bs + (wc*64 + ni*16 + l15)*32 + l4*8);
    #pragma unroll
    for (int mi = 0; mi < 4; ++mi)
      #pragma unroll
      for (int ni = 0; ni < 4; ++ni)
        acc[mi][ni] = __builtin_amdgcn_mfma_f32_16x16x32_bf16(af[mi], bfr[ni], acc[mi][ni], 0, 0, 0);
    __syncthreads();
  }
  #pragma unroll
  for (int mi = 0; mi < 4; ++mi)
    #pragma unroll
    for (int ni = 0; ni < 4; ++ni)
      #pragma unroll
      for (int j = 0; j < 4; ++j) {
        size_t p = p0 + wr*64 + mi*16 + l4*4 + j;
        int o = o0 + wc*64 + ni*16 + l15;
        C[p*512 + o] = acc[mi][ni][j];
      }
}

// ============ stats1: algebraic BN1 sums over u (one h1u read) ==============
__global__ __launch_bounds__(256) void stats1_kernel(
    const float* __restrict__ h1u, const float* __restrict__ L4,
    const float* __restrict__ w1l, float* __restrict__ sums) {
  int t = threadIdx.x;
  int c2 = t*2;
  int u0 = blockIdx.x * 16;
  float w0a = w1l[c2*3],     w1a = w1l[c2*3+1],     w2a = w1l[c2*3+2];
  float w0b = w1l[(c2+1)*3], w1b = w1l[(c2+1)*3+1], w2b = w1l[(c2+1)*3+2];
  float s0=0.f, s1=0.f, q0=0.f, q1=0.f;
  #pragma unroll 4
  for (int j = 0; j < 16; ++j) {
    int u = u0 + j;
    float4 Lc = *(const float4*)(L4 + (size_t)u*4);
    float2 h = *(const float2*)(h1u + (size_t)u*512 + c2);
    float lwa = Lc.x*w0a + Lc.y*w1a + Lc.z*w2a;
    float lwb = Lc.x*w0b + Lc.y*w1b + Lc.z*w2b;
    s0 += Lc.w*h.x;  q0 += Lc.w*h.x*h.x + 2.f*h.x*lwa;
    s1 += Lc.w*h.y;  q1 += Lc.w*h.y*h.y + 2.f*h.y*lwb;
  }
  atomicAdd(&sums[c2],       s0);
  atomicAdd(&sums[c2+1],     s1);
  atomicAdd(&sums[512+c2],   q0);
  atomicAdd(&sums[512+c2+1], q1);
}

// ---- finalize1: BN1 scale/shift + folded local weights w1ls = sc*w1l -------
__global__ void finalize1_kernel(const float* __restrict__ sums,
                                 const float* __restrict__ GM,
                                 const float* __restrict__ w1l,
                                 const float* __restrict__ g,
                                 const float* __restrict__ bia,
                                 float* __restrict__ ss,
                                 float* __restrict__ w1ls) {
  int c = blockIdx.x*256 + threadIdx.x;
  if (c >= 512) return;
  float w0 = w1l[c*3], w1 = w1l[c*3+1], w2 = w1l[c*3+2];
  float S = sums[c] + w0*GM[0] + w1*GM[1] + w2*GM[2];
  float Q = sums[512+c] + w0*w0*GM[3] + 2.f*w0*w1*GM[4] + 2.f*w0*w2*GM[5]
                        + w1*w1*GM[6] + 2.f*w1*w2*GM[7] + w2*w2*GM[8];
  const float invN = 1.f / (float)P_TOT;
  float mean = S * invN;
  float var  = Q * invN - mean*mean;
  float sc = g[c] * rsqrtf(var + 1e-5f);
  ss[c] = sc;
  ss[512+c] = bia[c] - mean*sc;
  w1ls[c]        = sc * w0;   // planar [3][512]
  w1ls[512 + c]  = sc * w1;
  w1ls[1024 + c] = sc * w2;
}

// ---- fold: h1u <- sc*h1u + sh (in place; BN1 affine folded into operand) ---
__global__ __launch_bounds__(256) void fold_kernel(float* __restrict__ h1u,
                                                   const float* __restrict__ ss) {
  size_t i = ((size_t)blockIdx.x*256 + threadIdx.x) * 4;   // 2048 blocks
  int c = (int)(i & 511);
  float4 v = *(float4*)(h1u + i);
  float4 sc = *(const float4*)(ss + c);
  float4 sh = *(const float4*)(ss + 512 + c);
  v.x = fmaf(v.x, sc.x, sh.x);
  v.y = fmaf(v.y, sc.y, sh.y);
  v.z = fmaf(v.z, sc.z, sh.z);
  v.w = fmaf(v.w, sc.w, sh.w);
  *(float4*)(h1u + i) = v;
}

__global__ void finalize_kernel(const float* __restrict__ sums,
                                const float* __restrict__ g,
                                const float* __restrict__ bia,
                                float* __restrict__ ss) {
  int c = blockIdx.x*256 + threadIdx.x;
  if (c >= 512) return;
  const float invN = 1.f / (float)P_TOT;
  float mean = sums[c] * invN;
  float var  = sums[512+c] * invN - mean*mean;
  float sc = g[c] * rsqrtf(var + 1e-5f);
  ss[c] = sc;
  ss[512+c] = bia[c] - mean*sc;
}

// ============ GEMM2 v5: 128x256 tile, 8 waves (2x4), swizzled LDS ===========
// A = relu(h1u'[u] + l·w1ls) -> bf16. Halves A-transform redundancy (2 o-blocks
// instead of 4 share each p-tile); per-wave fragment structure unchanged.
__global__ __launch_bounds__(512) void gemm2_kernel(
    const float* __restrict__ h1u,    // (4096, 512) f32 FOLDED
    const int* __restrict__ idx,      // (P)
    const float* __restrict__ lxyz,   // (P, 3)
    const float* __restrict__ w1ls,   // [3][512] folded local weights
    const unsigned short* __restrict__ Bw,    // (512, 512) bf16
    float* __restrict__ sums,                 // BN2 stats
    float* __restrict__ pmax,                 // (4096, 512)
    float* __restrict__ pmin)
{
  __shared__ unsigned short As[128*32];    // 8 KB
  __shared__ unsigned short Bs[256*32];    // 16 KB
  __shared__ float wl[1536];               // 6 KB
  int bx = blockIdx.x;
  int ob = bx & 1;
  size_t p0 = (size_t)(bx >> 1) * 128;
  int o0 = ob * 256;
  int t = threadIdx.x;                     // 512 threads = 8 waves
  int w = t >> 6, lane = t & 63;
  int wr = w >> 2;                         // 0..1 (p dim)
  int wc = w & 3;                          // 0..3 (o dim)
  int l15 = lane & 15, l4 = lane >> 4;
  f32x4 acc[4][4];
  f32x4 zf = {0.f, 0.f, 0.f, 0.f};
  #pragma unroll
  for (int mi = 0; mi < 4; ++mi)
    #pragma unroll
    for (int ni = 0; ni < 4; ++ni) acc[mi][ni] = zf;

  int sl = (lane & 3) ^ ((lane >> 3) & 3);   // swizzled 16B slot
  int scole = (lane & 3) * 8;
  int cA = (l4 ^ ((l15 >> 1) & 3)) * 8;      // swizzled read elem offset

  // wl: planar [3][512]
  wl[t] = w1ls[t]; wl[512 + t] = w1ls[512 + t]; wl[1024 + t] = w1ls[1024 + t];

  // A: one 16-row chunk per wave (chunk = w); per lane: row = 16w + (lane>>2)
  int arow = 16*w + (lane >> 2);
  int awoff = arow*64 + sl*16;               // swizzled As write byte offset
  const float* hptr;
  float lxr, lyr, lzr;
  {
    size_t p = p0 + arow;
    int b = (int)(p >> 15);
    int n = idx[p];
    hptr = h1u + (((size_t)b << 10) + n)*512 + scole;
    const float* lwp = lxyz + p*3;
    lxr = lwp[0]; lyr = lwp[1]; lzr = lwp[2];
  }
  // B: two 16-row chunks per wave (c = 2w+cc); pre-swizzled global source
  const unsigned short* bptr[2];
  #pragma unroll
  for (int cc = 0; cc < 2; ++cc) {
    int brow = 16*(2*w + cc) + (lane >> 2);
    bptr[cc] = Bw + (size_t)(o0 + brow)*CIN + sl*8;
  }

  float4 hv0 = *(const float4*)(hptr);
  float4 hv1 = *(const float4*)(hptr + 4);
  __syncthreads();   // wl staged

  for (int k0 = 0; k0 < CIN; k0 += 32) {
    #pragma unroll
    for (int cc = 0; cc < 2; ++cc)
      load_lds16(bptr[cc] + k0, (char*)Bs + (2*w + cc)*1024);   // linear dest
    // folded local-weight tables for channels k0+scole..+7
    int ch0 = k0 + scole;
    float4 xa = *(const float4*)(wl + ch0);
    float4 xb = *(const float4*)(wl + ch0 + 4);
    float4 ya = *(const float4*)(wl + 512 + ch0);
    float4 yb = *(const float4*)(wl + 512 + ch0 + 4);
    float4 za = *(const float4*)(wl + 1024 + ch0);
    float4 zb = *(const float4*)(wl + 1024 + ch0 + 4);
    float w0[8] = {xa.x,xa.y,xa.z,xa.w,xb.x,xb.y,xb.z,xb.w};
    float w1[8] = {ya.x,ya.y,ya.z,ya.w,yb.x,yb.y,yb.z,yb.w};
    float w2[8] = {za.x,za.y,za.z,za.w,zb.x,zb.y,zb.z,zb.w};
    {
      float fv[8] = {hv0.x, hv0.y, hv0.z, hv0.w, hv1.x, hv1.y, hv1.z, hv1.w};
      float gv[8];
      #pragma unroll
      for (int e = 0; e < 8; ++e)
        gv[e] = fmaxf(fv[e] + lxr*w0[e] + lyr*w1[e] + lzr*w2[e], 0.f);
      unsigned int rv[4];
      #pragma unroll
      for (int j = 0; j < 4; ++j) rv[j] = cvtpk(gv[2*j], gv[2*j+1]);
      *(uint4*)((char*)As + awoff) = make_uint4(rv[0], rv[1], rv[2], rv[3]);
    }
    if (k0 + 32 < CIN) {
      hv0 = *(const float4*)(hptr + k0 + 32);
      hv1 = *(const float4*)(hptr + k0 + 36);
    }
    __syncthreads();
    short8 af[4], bfr[4];
    #pragma unroll
    for (int mi = 0; mi < 4; ++mi)
      af[mi] = *(const short8*)(As + (wr*64 + mi*16 + l15)*32 + cA);
    #pragma unroll
    for (int ni = 0; ni < 4; ++ni)
      bfr[ni] = *(const short8*)(Bs + (wc*64 + ni*16 + l15)*32 + cA);
    #pragma unroll
    for (int mi = 0; mi < 4; ++mi)
      #pragma unroll
      for (int ni = 0; ni < 4; ++ni)
        acc[mi][ni] = __builtin_amdgcn_mfma_f32_16x16x32_bf16(af[mi], bfr[ni], acc[mi][ni], 0, 0, 0);
    __syncthreads();
  }

  #pragma unroll
  for (int ni = 0; ni < 4; ++ni) {
    float s = 0.f, q = 0.f;
    #pragma unroll
    for (int mi = 0; mi < 4; ++mi)
      #pragma unroll
      for (int j = 0; j < 4; ++j) { float v = acc[mi][ni][j]; s += v; q += v*v; }
    s += __shfl_xor(s, 16); q += __shfl_xor(q, 16);
    s += __shfl_xor(s, 32); q += __shfl_xor(q, 32);
    if (l4 == 0) {
      int c = o0 + wc*64 + ni*16 + l15;
      atomicAdd(&sums[c], s);
      atomicAdd(&sums[512 + c], q);
    }
  }
  #pragma unroll
  for (int ni = 0; ni < 4; ++ni) {
    #pragma unroll
    for (int h = 0; h < 2; ++h) {
      float mx = -3.4e38f, mn = 3.4e38f;
      #pragma unroll
      for (int mi = 2*h; mi < 2*h + 2; ++mi)
        #pragma unroll
        for (int j = 0; j < 4; ++j) {
          float v = acc[mi][ni][j];
          mx = fmaxf(mx, v); mn = fminf(mn, v);
        }
      mx = fmaxf(mx, __shfl_xor(mx, 16)); mn = fminf(mn, __shfl_xor(mn, 16));
      mx = fmaxf(mx, __shfl_xor(mx, 32)); mn = fminf(mn, __shfl_xor(mn, 32));
      if (l4 == 0) {
        size_t bm = (p0 >> 5) + 2*wr + h;
        int o = o0 + wc*64 + ni*16 + l15;
        pmax[bm*512 + o] = mx;
        pmin[bm*512 + o] = mn;
      }
    }
  }
}

// ---------------- final: affine+relu on pooled, transpose to (B,512,M) ------
__global__ void final_transpose(const float* __restrict__ pmax,
                                const float* __restrict__ pmin,
                                const float* __restrict__ ss,
                                float* __restrict__ out) {
  __shared__ float tile[64][65];
  int b = blockIdx.z, ob = blockIdx.y, mb = blockIdx.x;
  int t = threadIdx.x, tr = t >> 6, tc = t & 63;
  #pragma unroll
  for (int j = 0; j < 16; ++j) {
    int m = mb*64 + j*4 + tr;
    int o = ob*64 + tc;
    float sc = ss[o], sh = ss[512+o];
    size_t pi = (((size_t)b << 10) + m)*512 + o;
    float v = (sc >= 0.f) ? pmax[pi] : pmin[pi];
    tile[j*4+tr][tc] = fmaxf(fmaf(v, sc, sh), 0.f);
  }
  __syncthreads();
  #pragma unroll
  for (int j = 0; j < 16; ++j) {
    int o = ob*64 + j*4 + tr;
    out[((size_t)b*512 + o)*1024 + mb*64 + tc] = tile[tc][j*4+tr];
  }
}

extern "C" void kernel_launch(void* const* d_in, const int* in_sizes, int n_in,
                              void* d_out, int out_size, void* d_ws, size_t ws_size,
                              hipStream_t stream) {
  const float* xyz   = (const float*)d_in[0];
  const float* feats = (const float*)d_in[1];
  const float* rot   = (const float*)d_in[2];
  const float* W1    = (const float*)d_in[3];
  const float* g1    = (const float*)d_in[4];
  const float* b1    = (const float*)d_in[5];
  const float* W2    = (const float*)d_in[6];
  const float* g2    = (const float*)d_in[7];
  const float* b2    = (const float*)d_in[8];
  float* out = (float*)d_out;
  char* wsb = (char*)d_ws;

  const size_t OFF_IDX    = 0;                                          // 512 KB
  const size_t OFF_LXYZ   = OFF_IDX    + (size_t)P_TOT*4;               // 1.5 MB
  const size_t OFF_FEATST = OFF_LXYZ   + (size_t)P_TOT*3*4;             // 4.2 MB
  const size_t OFF_W1F    = OFF_FEATST + (size_t)BATCH*NPTS*CIN*2;      // 512 KB
  const size_t OFF_W1L    = OFF_W1F    + (size_t)CO*512*2;              // 8 KB
  const size_t OFF_W1LS   = OFF_W1L    + 8192;                          // 8 KB
  const size_t OFF_W2B    = OFF_W1LS   + 8192;                          // 512 KB
  const size_t OFF_STATS  = OFF_W2B    + (size_t)CO*CIN*2;              // 16 KB
  const size_t OFF_L4     = OFF_STATS  + 16384;                         // 64 KB
  const size_t OFF_GM     = OFF_L4     + 65536;                         // 4 KB
  const size_t OFF_H1U    = OFF_GM     + 4096;                          // 8 MB
  const size_t OFF_PMAX   = OFF_H1U    + (size_t)BATCH*NPTS*CO*4;       // 8 MB
  const size_t OFF_PMIN   = OFF_PMAX   + (size_t)BATCH*NPTS*CO*4;       // 8 MB
  const size_t WS_NEED    = OFF_PMIN   + (size_t)BATCH*NPTS*CO*4;       // ~31 MiB

  if (ws_size < WS_NEED) return;   // diagnostic guard

  int* idx             = (int*)(wsb + OFF_IDX);
  float* lxyz          = (float*)(wsb + OFF_LXYZ);
  unsigned short* fT   = (unsigned short*)(wsb + OFF_FEATST);
  unsigned short* w1f  = (unsigned short*)(wsb + OFF_W1F);
  float* w1l           = (float*)(wsb + OFF_W1L);
  float* w1ls          = (float*)(wsb + OFF_W1LS);
  unsigned short* w2b  = (unsigned short*)(wsb + OFF_W2B);
  float* stats         = (float*)(wsb + OFF_STATS);
  float* sums1 = stats;
  float* ss1   = stats + 1024;
  float* sums2 = stats + 2048;
  float* ss2   = stats + 3072;
  float* L4            = (float*)(wsb + OFF_L4);
  float* GM            = (float*)(wsb + OFF_GM);
  float* h1u           = (float*)(wsb + OFF_H1U);
  float* pmax          = (float*)(wsb + OFF_PMAX);
  float* pmin          = (float*)(wsb + OFF_PMIN);

  hipMemsetAsync(stats, 0, 16384 + 65536 + 4096, stream);

  transpose_feats<<<dim3(NPTS/64, CIN/64, BATCH), 256, 0, stream>>>(feats, fT);
  cyl_query_kernel<<<BATCH*NPTS, 64, 0, stream>>>(xyz, rot, idx, lxyz);
  build_w1<<<(512*512 + 255)/256, 256, 0, stream>>>(W1, w1f, w1l);
  build_w2<<<(CO*CIN + 255)/256, 256, 0, stream>>>(W2, w2b);

  scatter_kernel<<<P_TOT/256, 256, 0, stream>>>(idx, lxyz, L4, GM);
  gemm1u_kernel<<<(BATCH*NPTS/128)*4, 256, 0, stream>>>(fT, w1f, h1u);
  stats1_kernel<<<256, 256, 0, stream>>>(h1u, L4, w1l, sums1);
  finalize1_kernel<<<2, 256, 0, stream>>>(sums1, GM, w1l, g1, b1, ss1, w1ls);
  fold_kernel<<<(BATCH*NPTS*CO/4)/256, 256, 0, stream>>>(h1u, ss1);

  gemm2_kernel<<<(P_TOT/128)*2, 512, 0, stream>>>(h1u, idx, lxyz, w1ls, w2b,
                                                  sums2, pmax, pmin);
  finalize_kernel<<<2, 256, 0, stream>>>(sums2, g2, b2, ss2);

  final_transpose<<<dim3(NPTS/64, CO/64, BATCH), 256, 0, stream>>>(pmax, pmin, ss2, out);
}